// Round 11
// baseline (38.946 us; speedup 1.0000x reference)
//
#include <hip/hip_runtime.h>

// 4-level MoE routing loss, B=8, H=1024, ROUTE=64, 16x16 patches/level.
// d_in: out0, gt0, out1, gt1, out2, gt2, out3, gt3   (all fp32)
// d_out (fp32 flat): [0] loss | [1..8388609) label_patch (8,1024,1024)
//   | [+2048) moe_label as float | [+8192) score (8,4,16,16)
// ws: double lossTerm[2048] @0 (16KB).
//
// R11 = exact R9 (best structure: 30.1us) + NON-TEMPORAL label stores.
//   Rationale: inputs (89MB) + outputs (37.5MB) both fit in 256MB L3, yet
//   steady-state FETCH ~46MB -> the label-write stream evicts inputs.
//   NT stores bypass L2/L3: writes stream to HBM, inputs stay L3-resident
//   across timed replays -> reads at L3 BW, no capacity contention.
// Kept: XCD row-swizzle (seam-merge), 3/60/1 aligned-quad store split,
//   per-block lossTerm -> 1-block deterministic reduce.
// Banned (falsified): returning hot-line atomics (R4/R8), device fences /
//   grid.sync (R3), wave-per-patch (R10), cross-block rendezvous of any kind.

#define NPATCH 2048

typedef float f4v __attribute__((ext_vector_type(4)));

__global__ __launch_bounds__(256) void fused_kernel(
    const float* __restrict__ out0, const float* __restrict__ gt0,
    const float* __restrict__ out1, const float* __restrict__ gt1,
    const float* __restrict__ out2, const float* __restrict__ gt2,
    const float* __restrict__ out3, const float* __restrict__ gt3,
    float* __restrict__ scoreOut,   // (B,4,16,16)
    float* __restrict__ moeF,       // moe_label as float
    float* __restrict__ lab,        // label_patch base (d_out+1)
    double* __restrict__ lossTerm)  // ws [2048]
{
    // XCD row-swizzle: all px of one (b,py) tile-row share an XCD.
    const int q = blockIdx.x;
    const int px = q >> 7;             // 0..15
    const int row = q & 127;           // b*16 + py
    const int b = row >> 4;
    const int py = row & 15;
    const int l = (py << 4) | px;
    const int p = (b << 8) | l;        // logical patch id for moe/lossTerm

    const float* PO[4] = {out0, out1, out2, out3};
    const float* PG[4] = {gt0, gt1, gt2, gt3};

    float err[4], gts[4];

    #pragma unroll
    for (int lev = 0; lev < 4; ++lev) {
        const int k  = 64 >> lev;          // compile-time per unrolled iter
        const int W  = 1024 >> lev;
        const int kv = k >> 2;
        const int nvec = k * kv;
        const int rowBase = py * k, colBase = px * k;
        const size_t base = (size_t)b * W * W;
        const float* po = PO[lev];
        const float* pg = PG[lev];

        float e = 0.f, g = 0.f;
        for (int idx = threadIdx.x; idx < nvec; idx += 256) {
            int r = idx / kv;
            int c = (idx % kv) * 4;
            size_t off = base + (size_t)(rowBase + r) * W + (colBase + c);
            float4 o = *(const float4*)(po + off);
            float4 qv = *(const float4*)(pg + off);
            float dx = o.x - qv.x, dy = o.y - qv.y, dz = o.z - qv.z, dw = o.w - qv.w;
            e += dx * dx + dy * dy + dz * dz + dw * dw;
            g += qv.x + qv.y + qv.z + qv.w;
        }
        err[lev] = e; gts[lev] = g;
    }

    for (int s = 32; s; s >>= 1) {
        #pragma unroll
        for (int i = 0; i < 4; ++i) {
            err[i] += __shfl_down(err[i], s, 64);
            gts[i] += __shfl_down(gts[i], s, 64);
        }
    }
    __shared__ float se[4][4], sg[4][4];
    __shared__ int smv;
    const int wave = threadIdx.x >> 6, lane = threadIdx.x & 63;
    if (lane == 0) {
        #pragma unroll
        for (int i = 0; i < 4; ++i) { se[i][wave] = err[i]; sg[i][wave] = gts[i]; }
    }
    __syncthreads();
    if (threadIdx.x == 0) {
        float E[4], S[4];
        #pragma unroll
        for (int i = 0; i < 4; ++i) {
            E[i] = se[i][0] + se[i][1] + se[i][2] + se[i][3];
            float G = sg[i][0] + sg[i][1] + sg[i][2] + sg[i][3];
            float kk = (float)((64 >> i) * (64 >> i));
            S[i] = E[i] / kk + E[i] / (G + 1e-10f);
            scoreOut[b * 1024 + i * 256 + l] = S[i];
        }
        int m = 0; float best = S[0];
        #pragma unroll
        for (int i = 1; i < 4; ++i)
            if (S[i] < best) { best = S[i]; m = i; }   // strict <, first-min
        moeF[p] = (float)m;
        smv = m;
        double t = (double)E[0] / 8388608.0;
        if (m >= 1) t += (double)E[1] / 2097152.0;
        if (m >= 2) t += (double)E[2] / 524288.0;
        if (m >= 3) t += (double)E[3] / 131072.0;
        lossTerm[p] = t;
    }
    __syncthreads();
    const int m = smv;

    // ---- phase 2: write own 64x64 label tile, NON-TEMPORAL stores ----
    // lab row start R0 = labBase + y*1024 (R0 % 4 == 0); d_out = lab+1 so
    // aligned float4 slots are lab[3+4j .. 6+4j], j=0..14; remainders are
    // lab[R0+0..2] and lab[R0+63].
    const size_t labBase = (size_t)b * 1048576 + (size_t)(py << 6) * 1024 + (px << 6);

    if (m == 0) {
        for (int idx = threadIdx.x; idx < 1024; idx += 256) {
            int y = idx >> 4, j = idx & 15;
            size_t R0 = labBase + (size_t)y * 1024;
            if (j < 15) {
                int x = 3 + 4 * j;
                f4v v;
                v.x = gt0[R0 + x];
                v.y = gt0[R0 + x + 1];
                v.z = gt0[R0 + x + 2];
                v.w = gt0[R0 + x + 3];
                __builtin_nontemporal_store(v, (f4v*)(lab + R0 + x));
            } else {
                __builtin_nontemporal_store(gt0[R0],      lab + R0);
                __builtin_nontemporal_store(gt0[R0 + 1],  lab + R0 + 1);
                __builtin_nontemporal_store(gt0[R0 + 2],  lab + R0 + 2);
                __builtin_nontemporal_store(gt0[R0 + 63], lab + R0 + 63);
            }
        }
    } else {
        const int k = 64 >> m, pad = (64 - k) >> 1, W = 1024 >> m;
        const float* gt = (m == 1) ? gt1 : (m == 2) ? gt2 : gt3;
        const size_t gbase = (size_t)b * W * W + (size_t)(py * k) * W + px * k;
        for (int idx = threadIdx.x; idx < 1024; idx += 256) {
            int y = idx >> 4, j = idx & 15;
            size_t R0 = labBase + (size_t)y * 1024;
            int iy = y - pad;
            bool rowIn = (unsigned)iy < (unsigned)k;
            const float* grow = gt + gbase + (size_t)iy * W;
            if (j < 15) {
                int x = 3 + 4 * j;
                f4v v;
                #pragma unroll
                for (int u = 0; u < 4; ++u) {
                    int ix = x + u - pad;
                    float vv = 0.2f;
                    if (rowIn && (unsigned)ix < (unsigned)k) vv = grow[ix];
                    v[u] = vv;
                }
                __builtin_nontemporal_store(v, (f4v*)(lab + R0 + x));
            } else {
                #pragma unroll
                for (int u = 0; u < 3; ++u) {
                    int ix = u - pad;
                    float vv = 0.2f;
                    if (rowIn && (unsigned)ix < (unsigned)k) vv = grow[ix];
                    __builtin_nontemporal_store(vv, lab + R0 + u);
                }
                int ix = 63 - pad;
                float vv = 0.2f;
                if (rowIn && (unsigned)ix < (unsigned)k) vv = grow[ix];
                __builtin_nontemporal_store(vv, lab + R0 + 63);
            }
        }
    }
}

__global__ __launch_bounds__(256) void loss_kernel(
    const double* __restrict__ lossTerm, float* __restrict__ lossOut)
{
    double t = 0.0;
    for (int i = threadIdx.x; i < NPATCH; i += 256) t += lossTerm[i];
    for (int s = 32; s; s >>= 1) t += __shfl_down(t, s, 64);
    __shared__ double sd[4];
    const int wave = threadIdx.x >> 6, lane = threadIdx.x & 63;
    if (lane == 0) sd[wave] = t;
    __syncthreads();
    if (threadIdx.x == 0)
        lossOut[0] = (float)(sd[0] + sd[1] + sd[2] + sd[3]);
}

extern "C" void kernel_launch(void* const* d_in, const int* in_sizes, int n_in,
                              void* d_out, int out_size, void* d_ws, size_t ws_size,
                              hipStream_t stream) {
    const float* out0 = (const float*)d_in[0];
    const float* gt0  = (const float*)d_in[1];
    const float* out1 = (const float*)d_in[2];
    const float* gt1  = (const float*)d_in[3];
    const float* out2 = (const float*)d_in[4];
    const float* gt2  = (const float*)d_in[5];
    const float* out3 = (const float*)d_in[6];
    const float* gt3  = (const float*)d_in[7];

    float* o = (float*)d_out;
    float* lossOut  = o;
    float* labOut   = o + 1;
    float* moeFOut  = o + 8388609;
    float* scoreOut = o + 8390657;

    double* lossTerm = (double*)d_ws;

    fused_kernel<<<NPATCH, 256, 0, stream>>>(
        out0, gt0, out1, gt1, out2, gt2, out3, gt3,
        scoreOut, moeFOut, labOut, lossTerm);
    loss_kernel<<<1, 256, 0, stream>>>(lossTerm, lossOut);
}

// Round 13
// 30.923 us; speedup vs baseline: 1.2595x; 1.2595x over previous
//
#include <hip/hip_runtime.h>

// 4-level MoE routing loss, B=8, H=1024, ROUTE=64, 16x16 patches/level.
// d_in: out0, gt0, out1, gt1, out2, gt2, out3, gt3   (all fp32)
// d_out (fp32 flat): [0] loss | [1..8388609) label_patch (8,1024,1024)
//   | [+2048) moe_label as float | [+8192) score (8,4,16,16)
// ws: double lossTerm[2048] @0 (16KB).
//
// R13 = R9 (proven 30.1us) + register-reuse phase 2 via LDS restaging.
//   Phase 1: batch loads kept in registers (q0[4], q1, q2, q3); scalar
//     component FP arithmetic BITWISE-IDENTICAL to R9 (same sum order) so
//     scores/argmin can't drift.
//   Phase 2: build the 64x64 tile in __shared__ from registers only
//     (R12's center/pad maps — hand-verified; all LDS writes 16B-aligned),
//     one barrier, then R9's PROVEN global store pattern: 15 quads at
//     lab[3+4j] (d_out byte % 16 == 0) + 4 scalars per row, values from LDS.
//   ZERO phase-2 global loads.
// LESSON (R12): 16B global stores at byte%16!=0 CORRUPT — alignment must
//   be true in d_out byte space. lab[3+4j] slots only.
// Banned (falsified): returning hot-line atomics (R4/R8), device fences
//   (R3), NT stores (R11), wave-per-patch (R10), unaligned dwordx4 (R12).

#define NPATCH 2048

__global__ __launch_bounds__(256) void fused_kernel(
    const float* __restrict__ out0, const float* __restrict__ gt0,
    const float* __restrict__ out1, const float* __restrict__ gt1,
    const float* __restrict__ out2, const float* __restrict__ gt2,
    const float* __restrict__ out3, const float* __restrict__ gt3,
    float* __restrict__ scoreOut,   // (B,4,16,16)
    float* __restrict__ moeF,       // moe_label as float
    float* __restrict__ lab,        // label_patch base (d_out+1)
    double* __restrict__ lossTerm)  // ws [2048]
{
    __shared__ float tile[64][64];     // 16KB staging (16B-aligned rows)
    __shared__ float se[4][4], sg[4][4];
    __shared__ int smv;

    // XCD row-swizzle (R9): all px of one (b,py) tile-row share an XCD.
    const int q = blockIdx.x;
    const int px = q >> 7;             // 0..15
    const int row = q & 127;           // b*16 + py
    const int b = row >> 4;
    const int py = row & 15;
    const int l = (py << 4) | px;
    const int p = (b << 8) | l;        // logical patch id
    const int t = threadIdx.x;

    float err[4] = {0.f, 0.f, 0.f, 0.f}, gts[4] = {0.f, 0.f, 0.f, 0.f};

    // ---- phase 1 (R9 FP order, loads kept in registers) ----
    // level 0: 1024 quads, 4/thread at idx = t + 256*it (same order as R9)
    float4 q0[4];
    {
        const size_t base = (size_t)b * 1048576;
        const int rb = py << 6, cb = px << 6;
        float e = 0.f, g = 0.f;
        #pragma unroll
        for (int it = 0; it < 4; ++it) {
            int idx = t + (it << 8);
            int r = idx >> 4, c = (idx & 15) << 2;
            size_t off = base + (size_t)(rb + r) * 1024 + (cb + c);
            float4 o = *(const float4*)(out0 + off);
            float4 qv = *(const float4*)(gt0 + off);
            q0[it] = qv;
            float dx = o.x - qv.x, dy = o.y - qv.y, dz = o.z - qv.z, dw = o.w - qv.w;
            e += dx * dx + dy * dy + dz * dz + dw * dw;
            g += qv.x + qv.y + qv.z + qv.w;
        }
        err[0] = e; gts[0] = g;
    }
    // level 1: 256 quads, 1/thread (r = t>>3, c = (t&7)*4 == R9's idx map)
    float4 q1;
    {
        const size_t base = (size_t)b * 262144;
        int r = t >> 3, c = (t & 7) << 2;
        size_t off = base + (size_t)((py << 5) + r) * 512 + ((px << 5) + c);
        float4 o = *(const float4*)(out1 + off);
        q1 = *(const float4*)(gt1 + off);
        float dx = o.x - q1.x, dy = o.y - q1.y, dz = o.z - q1.z, dw = o.w - q1.w;
        err[1] = dx * dx + dy * dy + dz * dz + dw * dw;
        gts[1] = q1.x + q1.y + q1.z + q1.w;
    }
    // level 2: 64 quads, threads 0..63 (== R9 participants)
    float4 q2 = {0.f, 0.f, 0.f, 0.f};
    if (t < 64) {
        const size_t base = (size_t)b * 65536;
        int r = t >> 2, c = (t & 3) << 2;
        size_t off = base + (size_t)((py << 4) + r) * 256 + ((px << 4) + c);
        float4 o = *(const float4*)(out2 + off);
        q2 = *(const float4*)(gt2 + off);
        float dx = o.x - q2.x, dy = o.y - q2.y, dz = o.z - q2.z, dw = o.w - q2.w;
        err[2] = dx * dx + dy * dy + dz * dz + dw * dw;
        gts[2] = q2.x + q2.y + q2.z + q2.w;
    }
    // level 3: 16 quads, threads 0..15 (== R9 participants)
    float4 q3 = {0.f, 0.f, 0.f, 0.f};
    if (t < 16) {
        const size_t base = (size_t)b * 16384;
        int r = t >> 1, c = (t & 1) << 2;
        size_t off = base + (size_t)((py << 3) + r) * 128 + ((px << 3) + c);
        float4 o = *(const float4*)(out3 + off);
        q3 = *(const float4*)(gt3 + off);
        float dx = o.x - q3.x, dy = o.y - q3.y, dz = o.z - q3.z, dw = o.w - q3.w;
        err[3] = dx * dx + dy * dy + dz * dz + dw * dw;
        gts[3] = q3.x + q3.y + q3.z + q3.w;
    }

    // ---- reduce + t0 section (exact R9) ----
    for (int s = 32; s; s >>= 1) {
        #pragma unroll
        for (int i = 0; i < 4; ++i) {
            err[i] += __shfl_down(err[i], s, 64);
            gts[i] += __shfl_down(gts[i], s, 64);
        }
    }
    const int wave = t >> 6, lane = t & 63;
    if (lane == 0) {
        #pragma unroll
        for (int i = 0; i < 4; ++i) { se[i][wave] = err[i]; sg[i][wave] = gts[i]; }
    }
    __syncthreads();
    if (t == 0) {
        float E[4], S[4];
        #pragma unroll
        for (int i = 0; i < 4; ++i) {
            E[i] = se[i][0] + se[i][1] + se[i][2] + se[i][3];
            float G = sg[i][0] + sg[i][1] + sg[i][2] + sg[i][3];
            float kk = (float)((64 >> i) * (64 >> i));
            S[i] = E[i] / kk + E[i] / (G + 1e-10f);
            scoreOut[b * 1024 + i * 256 + l] = S[i];
        }
        int m = 0; float best = S[0];
        #pragma unroll
        for (int i = 1; i < 4; ++i)
            if (S[i] < best) { best = S[i]; m = i; }   // strict <, first-min
        moeF[p] = (float)m;
        smv = m;
        double tt = (double)E[0] / 8388608.0;
        if (m >= 1) tt += (double)E[1] / 2097152.0;
        if (m >= 2) tt += (double)E[2] / 524288.0;
        if (m >= 3) tt += (double)E[3] / 131072.0;
        lossTerm[p] = tt;
    }
    __syncthreads();
    const int m = smv;                 // block-uniform

    // ---- phase 2a: build tile in LDS from registers (disjoint writes) ----
    const float4 pv = {0.2f, 0.2f, 0.2f, 0.2f};
    if (m == 0) {
        #pragma unroll
        for (int it = 0; it < 4; ++it) {
            int idx = t + (it << 8);
            int r = idx >> 4, c = (idx & 15) << 2;
            *(float4*)&tile[r][c] = q0[it];
        }
    } else if (m == 1) {
        { int r = t >> 3, c = (t & 7) << 2; *(float4*)&tile[16 + r][16 + c] = q1; }
        #pragma unroll
        for (int z = 0; z < 3; ++z) {      // 768 pad quads
            int idx = t + (z << 8);
            int prow, pcol;
            if (idx < 256)      { prow = idx >> 4;                pcol = (idx & 15) << 2; }
            else if (idx < 512) { int w = idx - 256; prow = 48 + (w >> 4); pcol = (w & 15) << 2; }
            else                { int w = idx - 512; prow = 16 + (w >> 3);
                                  int s = w & 7; pcol = (s < 4) ? (s << 2) : (48 + ((s - 4) << 2)); }
            *(float4*)&tile[prow][pcol] = pv;
        }
    } else if (m == 2) {
        if (t < 64) { int r = t >> 2, c = (t & 3) << 2; *(float4*)&tile[24 + r][24 + c] = q2; }
        for (int idx = t; idx < 960; idx += 256) {   // 960 pad quads
            int prow, pcol;
            if (idx < 384)      { prow = idx >> 4;                pcol = (idx & 15) << 2; }
            else if (idx < 768) { int w = idx - 384; prow = 40 + (w >> 4); pcol = (w & 15) << 2; }
            else                { int w = idx - 768; prow = 24 + w / 12;
                                  int s = w % 12; pcol = (s < 6) ? (s << 2) : (40 + ((s - 6) << 2)); }
            *(float4*)&tile[prow][pcol] = pv;
        }
    } else {
        if (t < 16) { int r = t >> 1, c = (t & 1) << 2; *(float4*)&tile[28 + r][28 + c] = q3; }
        for (int idx = t; idx < 1008; idx += 256) {  // 1008 pad quads
            int prow, pcol;
            if (idx < 448)      { prow = idx >> 4;                pcol = (idx & 15) << 2; }
            else if (idx < 896) { int w = idx - 448; prow = 36 + (w >> 4); pcol = (w & 15) << 2; }
            else                { int w = idx - 896; prow = 28 + w / 14;
                                  int s = w % 14; pcol = (s < 7) ? (s << 2) : (36 + ((s - 7) << 2)); }
            *(float4*)&tile[prow][pcol] = pv;
        }
    }
    __syncthreads();

    // ---- phase 2b: aligned global stores (R9 pattern), values from LDS ----
    // Row y: quads at lab[R0 + 3+4j] (d_out byte % 16 == 0, PROVEN) +
    // scalars lab[R0 + {0,1,2,63}]. LDS reads are scalar (no b128 align req).
    const size_t labBase = (size_t)b * 1048576 + (size_t)(py << 6) * 1024 + (px << 6);
    for (int idx = t; idx < 1024; idx += 256) {
        int y = idx >> 4, j = idx & 15;
        size_t R0 = labBase + (size_t)y * 1024;
        if (j < 15) {
            int x = 3 + 4 * j;
            float4 v;
            v.x = tile[y][x];
            v.y = tile[y][x + 1];
            v.z = tile[y][x + 2];
            v.w = tile[y][x + 3];
            *(float4*)(lab + R0 + x) = v;
        } else {
            lab[R0]      = tile[y][0];
            lab[R0 + 1]  = tile[y][1];
            lab[R0 + 2]  = tile[y][2];
            lab[R0 + 63] = tile[y][63];
        }
    }
}

__global__ __launch_bounds__(256) void loss_kernel(
    const double* __restrict__ lossTerm, float* __restrict__ lossOut)
{
    double t = 0.0;
    for (int i = threadIdx.x; i < NPATCH; i += 256) t += lossTerm[i];
    for (int s = 32; s; s >>= 1) t += __shfl_down(t, s, 64);
    __shared__ double sd[4];
    const int wave = threadIdx.x >> 6, lane = threadIdx.x & 63;
    if (lane == 0) sd[wave] = t;
    __syncthreads();
    if (threadIdx.x == 0)
        lossOut[0] = (float)(sd[0] + sd[1] + sd[2] + sd[3]);
}

extern "C" void kernel_launch(void* const* d_in, const int* in_sizes, int n_in,
                              void* d_out, int out_size, void* d_ws, size_t ws_size,
                              hipStream_t stream) {
    const float* out0 = (const float*)d_in[0];
    const float* gt0  = (const float*)d_in[1];
    const float* out1 = (const float*)d_in[2];
    const float* gt1  = (const float*)d_in[3];
    const float* out2 = (const float*)d_in[4];
    const float* gt2  = (const float*)d_in[5];
    const float* out3 = (const float*)d_in[6];
    const float* gt3  = (const float*)d_in[7];

    float* o = (float*)d_out;
    float* lossOut  = o;
    float* labOut   = o + 1;
    float* moeFOut  = o + 8388609;
    float* scoreOut = o + 8390657;

    double* lossTerm = (double*)d_ws;

    fused_kernel<<<NPATCH, 256, 0, stream>>>(
        out0, gt0, out1, gt1, out2, gt2, out3, gt3,
        scoreOut, moeFOut, labOut, lossTerm);
    loss_kernel<<<1, 256, 0, stream>>>(lossTerm, lossOut);
}